// Round 5
// baseline (322.273 us; speedup 1.0000x reference)
//
#include <hip/hip_runtime.h>
#include <hip/hip_cooperative_groups.h>
#include <hip/hip_bf16.h>
#include <stdint.h>

#define N_ 4096
#define D_ 128
#define C_ 400
#define TINV 10.0f
#define ALPHA_ 0.03f

typedef __bf16 bf16x8 __attribute__((ext_vector_type(8)));
typedef float f32x4 __attribute__((ext_vector_type(4)));

__device__ __forceinline__ void load16(const void* g, void* l) {
  __builtin_amdgcn_global_load_lds(
      (const __attribute__((address_space(1))) uint32_t*)g,
      (__attribute__((address_space(3))) uint32_t*)l, 16, 0, 0);
}

// =====================================================================
// Fused single cooperative kernel.
// Grid 512 x 256 threads. Block (rc, jb): rows rb=rc*64, col-block jb (512 cols).
// Phase 0: featB convert (f32->bf16, row-permuted) + CE partials.
// Phase A: Gram row sums R[g][jb] (+ partner P[g][jb]).
// Phase B: log-products (off-diag or 8-divisor diag variant + corr epilogue).
// Final:   block 0 reduces partials -> out (f32 scalar).
// =====================================================================
__global__ __launch_bounds__(256, 2) void k_all(
    const float* __restrict__ feat, const float* __restrict__ predicts,
    const int* __restrict__ labels, uint16_t* __restrict__ featB,
    float* __restrict__ R, float* __restrict__ P,
    double* __restrict__ p_nce, double* __restrict__ p_ce,
    float* __restrict__ out) {
  __shared__ alignas(16) uint16_t At[64 * 128];
  __shared__ alignas(16) uint16_t Bt[64 * 128];
  __shared__ double smr[8];
  cooperative_groups::grid_group grid = cooperative_groups::this_grid();
  const int t = threadIdx.x, bid = blockIdx.x;
  const int lane = t & 63, w = t >> 6;
  const int r0 = lane & 15, kq = lane >> 4, rq = kq << 2;
  const char* fb = (const char*)featB;

  // ---- Phase 0: convert + CE
  {
    int idx4 = bid * 256 + t;  // 0..131071 float4 tasks
    int nr = idx4 >> 5, d4 = idx4 & 31;
    int r = ((nr & 511) << 3) | (nr >> 9);
    float4 v = reinterpret_cast<const float4*>(feat)[r * 32 + d4];
    __hip_bfloat16 h0 = __float2bfloat16(v.x), h1 = __float2bfloat16(v.y),
                   h2 = __float2bfloat16(v.z), h3 = __float2bfloat16(v.w);
    ushort4 o;
    o.x = *(uint16_t*)&h0; o.y = *(uint16_t*)&h1;
    o.z = *(uint16_t*)&h2; o.w = *(uint16_t*)&h3;
    reinterpret_cast<ushort4*>(featB)[idx4] = o;

    double ce = 0.0;
#pragma unroll
    for (int s = 0; s < 2; ++s) {
      int row = bid * 8 + w * 2 + s;
      const float* pr = predicts + (size_t)row * C_;
      float mx = -3.0e38f;
      for (int k = lane; k < C_; k += 64) mx = fmaxf(mx, pr[k]);
#pragma unroll
      for (int o2 = 32; o2; o2 >>= 1) mx = fmaxf(mx, __shfl_xor(mx, o2));
      float sum = 0.f;
      for (int k = lane; k < C_; k += 64) sum += __expf(pr[k] - mx);
#pragma unroll
      for (int o2 = 32; o2; o2 >>= 1) sum += __shfl_xor(sum, o2);
      ce += (double)(__logf(sum) + mx - pr[labels[row]]);
    }
    if (lane == 0) smr[w] = ce;
    __syncthreads();
    if (t == 0) p_ce[bid] = smr[0] + smr[1] + smr[2] + smr[3];
  }
  __threadfence();
  grid.sync();

  const int rc = bid >> 3, jb = bid & 7;
  const int rb = rc << 6, cb = jb << 9;
  const int ib = rb >> 9, kbase = rb & 511;

  // A tile (64 rows), st-swizzled via inverse-swizzled global source
#pragma unroll
  for (int it = 0; it < 4; ++it) {
    int L = it * 4096 + t * 16;
    int row = L >> 8;
    int kbs = (L & 255) ^ ((row & 7) << 4);
    load16(fb + (size_t)(rb + row) * 256 + kbs, (char*)At + L);
  }
  __syncthreads();
  bf16x8 a[4];
  {
    int ra = (w << 4) + r0;
#pragma unroll
    for (int kk = 0; kk < 4; ++kk)
      a[kk] = *(const bf16x8*)((const char*)At + ra * 256 +
                               ((kk * 64 + kq * 16) ^ ((ra & 7) << 4)));
  }

#define LOADB64(colbase)                                                 \
  _Pragma("unroll") for (int it = 0; it < 4; ++it) {                     \
    int L = it * 4096 + t * 16;                                          \
    int row = L >> 8;                                                    \
    int kbs = (L & 255) ^ ((row & 7) << 4);                              \
    load16(fb + (size_t)((colbase) + row) * 256 + kbs, (char*)Bt + L);   \
  }

#define COMPUTE4()                                                            \
  _Pragma("unroll") for (int n = 0; n < 4; ++n) {                             \
    acc[n] = (f32x4)0.0f;                                                     \
    int cl = n * 16 + r0;                                                     \
    _Pragma("unroll") for (int kk = 0; kk < 4; ++kk) {                        \
      bf16x8 bfr = *(const bf16x8*)((const char*)Bt + cl * 256 +              \
                                    ((kk * 64 + kq * 16) ^ ((cl & 7) << 4))); \
      acc[n] =                                                                \
          __builtin_amdgcn_mfma_f32_16x16x32_bf16(a[kk], bfr, acc[n], 0, 0, 0); \
    }                                                                         \
  }

  // ---- Phase A: row sums + partner extraction
  {
    float rsum[4] = {0.f, 0.f, 0.f, 0.f};
    for (int t8 = 0; t8 < 8; ++t8) {
      __syncthreads();
      LOADB64(cb + t8 * 64);
      __syncthreads();
      f32x4 acc[4];
      COMPUTE4();
#pragma unroll
      for (int n = 0; n < 4; ++n)
#pragma unroll
        for (int q = 0; q < 4; ++q) {
          float v = __expf(acc[n][q] * TINV);
          rsum[q] += v;
          int rl = (w << 4) + rq + q;
          if (t8 * 64 + n * 16 + r0 == kbase + rl)
            P[(size_t)(rb + rl) * 8 + jb] = v;
        }
    }
#pragma unroll
    for (int q = 0; q < 4; ++q) {
      float s = rsum[q];
      s += __shfl_xor(s, 1); s += __shfl_xor(s, 2);
      s += __shfl_xor(s, 4); s += __shfl_xor(s, 8);
      if (r0 == 0) R[(size_t)(rb + (w << 4) + rq + q) * 8 + jb] = s;
    }
  }
  __threadfence();
  grid.sync();

  // ---- Phase B
  if (jb != ib) {
    float inv_[4], prod_[4];
#pragma unroll
    for (int q = 0; q < 4; ++q) {
      int g = rb + (w << 4) + rq + q;
      float Ri = R[(size_t)g * 8 + ib];
      float Rj = R[(size_t)g * 8 + jb];
      float Egg = P[(size_t)g * 8 + ib];
      inv_[q] = 1.f / (Ri + Rj - Egg);
      prod_[q] = 1.f;
    }
    for (int t8 = 0; t8 < 8; ++t8) {
      __syncthreads();
      LOADB64(cb + t8 * 64);
      __syncthreads();
      f32x4 acc[4];
      COMPUTE4();
#pragma unroll
      for (int n = 0; n < 4; ++n)
#pragma unroll
        for (int q = 0; q < 4; ++q)
          prod_[q] *= (1.f - __expf(acc[n][q] * TINV) * inv_[q]);
    }
    float lsum = 0.f;
#pragma unroll
    for (int q = 0; q < 4; ++q) {
      float pr2 = prod_[q];
      pr2 *= __shfl_xor(pr2, 1); pr2 *= __shfl_xor(pr2, 2);
      pr2 *= __shfl_xor(pr2, 4); pr2 *= __shfl_xor(pr2, 8);
      lsum += __logf(pr2);
    }
    if (r0 != 0) lsum = 0.f;
    lsum += __shfl_xor(lsum, 16);
    lsum += __shfl_xor(lsum, 32);
    if (lane == 0) smr[w] = (double)lsum;
    __syncthreads();
    if (t == 0) p_nce[bid] = smr[0] + smr[1] + smr[2] + smr[3];
  } else {
    float inv_[4][8], prod_[4][8];
#pragma unroll
    for (int q = 0; q < 4; ++q) {
      int g = rb + (w << 4) + rq + q;
      float Ri = R[(size_t)g * 8 + ib];
      float Egg = P[(size_t)g * 8 + ib];
#pragma unroll
      for (int j = 0; j < 8; ++j) {
        float Rj = R[(size_t)g * 8 + j];
        float dv = (j == ib) ? (2.f * Ri - Egg) : (Ri + Rj - Egg);
        inv_[q][j] = 1.f / dv;
        prod_[q][j] = 1.f;
      }
    }
    for (int t8 = 0; t8 < 8; ++t8) {
      __syncthreads();
      LOADB64(cb + t8 * 64);
      __syncthreads();
      f32x4 acc[4];
      COMPUTE4();
#pragma unroll
      for (int n = 0; n < 4; ++n)
#pragma unroll
        for (int q = 0; q < 4; ++q) {
          float e = __expf(acc[n][q] * TINV);
          int rl = (w << 4) + rq + q;
          if (t8 * 64 + n * 16 + r0 == kbase + rl) e = 0.f;  // exclude c==g
#pragma unroll
          for (int j = 0; j < 8; ++j) prod_[q][j] *= (1.f - e * inv_[q][j]);
        }
    }
    float lsum = 0.f;
#pragma unroll
    for (int q = 0; q < 4; ++q)
#pragma unroll
      for (int j = 0; j < 8; ++j) {
        float pr2 = prod_[q][j];
        pr2 *= __shfl_xor(pr2, 1); pr2 *= __shfl_xor(pr2, 2);
        pr2 *= __shfl_xor(pr2, 4); pr2 *= __shfl_xor(pr2, 8);
        float lg = __logf(pr2);
        lsum += (j == ib) ? 4.f * lg : lg;
      }
    if (r0 != 0) lsum = 0.f;
    lsum += __shfl_xor(lsum, 16);
    lsum += __shfl_xor(lsum, 32);
    // corr epilogue: 64 rows x 8 j for this block's rows
    float csum = 0.f;
#pragma unroll
    for (int s = 0; s < 2; ++s) {
      int task = (s << 8) + t;  // 0..511
      int rl = task >> 3, j = task & 7;
      int g = rb + rl;
      float Ri = R[(size_t)g * 8 + ib];
      float Egg = P[(size_t)g * 8 + ib];
      float val;
      if (j != ib) {
        float dv = Ri + R[(size_t)g * 8 + j] - Egg;
        float pmt = P[(size_t)g * 8 + j] / dv;
        val = __logf(pmt) - __logf(1.f - pmt);
      } else {
        float dv = 2.f * Ri - Egg;
        float pmt = Egg / dv;
        val = 2.f * __logf(pmt);
      }
      csum += val;
    }
#pragma unroll
    for (int o2 = 32; o2; o2 >>= 1) csum += __shfl_xor(csum, o2);
    if (lane == 0) smr[w] = (double)lsum + (double)csum;
    __syncthreads();
    if (t == 0) p_nce[bid] = smr[0] + smr[1] + smr[2] + smr[3];
  }
  __threadfence();
  grid.sync();

  // ---- Final reduce (block 0)
  if (bid == 0) {
    double nce = p_nce[t] + p_nce[t + 256];
    double ce = p_ce[t] + p_ce[t + 256];
#pragma unroll
    for (int o2 = 32; o2; o2 >>= 1) {
      nce += __shfl_xor(nce, o2);
      ce += __shfl_xor(ce, o2);
    }
    if (lane == 0) { smr[w] = nce; smr[4 + w] = ce; }
    __syncthreads();
    if (t == 0) {
      double tn = smr[0] + smr[1] + smr[2] + smr[3];
      double tc = smr[4] + smr[5] + smr[6] + smr[7];
      out[0] = ALPHA_ * (-(float)(tn / 1024.0)) + (float)(tc / 4096.0);
    }
  }
}

// =====================================================================
// Fallback path: verified round-4 multi-kernel pipeline (used only if the
// cooperative launch is rejected).
// =====================================================================
#define TILE_PREAMBLE()                                   \
  const int t = threadIdx.x;                              \
  const int lane = t & 63, w = t >> 6;                    \
  const int r0 = lane & 15, kq = lane >> 4, rq = kq << 2; \
  const char* fb = (const char*)featB;

#define LOAD_A(rbase)                                                  \
  _Pragma("unroll") for (int it = 0; it < 8; ++it) {                   \
    int L = it * 4096 + t * 16;                                        \
    int row = L >> 8;                                                  \
    int kbs = (L & 255) ^ ((row & 7) << 4);                            \
    load16(fb + (size_t)((rbase) + row) * 256 + kbs, (char*)At + L);   \
  }

#define LOAD_B(colbase)                                                \
  _Pragma("unroll") for (int it = 0; it < 4; ++it) {                   \
    int L = it * 4096 + t * 16;                                        \
    int row = L >> 8;                                                  \
    int kbs = (L & 255) ^ ((row & 7) << 4);                            \
    load16(fb + (size_t)((colbase) + row) * 256 + kbs, (char*)Bt + L); \
  }

#define READ_AFRAGS()                                                         \
  _Pragma("unroll") for (int m = 0; m < 2; ++m) {                             \
    int ra = w * 32 + m * 16 + r0;                                            \
    _Pragma("unroll") for (int kk = 0; kk < 4; ++kk)                          \
        a[m][kk] = *(const bf16x8*)((const char*)At + ra * 256 +              \
                                    ((kk * 64 + kq * 16) ^ ((ra & 7) << 4))); \
  }

#define COMPUTE_ACC()                                                           \
  _Pragma("unroll") for (int m = 0; m < 2; ++m)                                 \
      _Pragma("unroll") for (int n = 0; n < 4; ++n) acc[m][n] = (f32x4)0.0f;    \
  _Pragma("unroll") for (int n = 0; n < 4; ++n) {                               \
    bf16x8 bfr[4];                                                              \
    int cl = n * 16 + r0;                                                       \
    _Pragma("unroll") for (int kk = 0; kk < 4; ++kk)                            \
        bfr[kk] = *(const bf16x8*)((const char*)Bt + cl * 256 +                 \
                                   ((kk * 64 + kq * 16) ^ ((cl & 7) << 4)));    \
    _Pragma("unroll") for (int m = 0; m < 2; ++m)                               \
        _Pragma("unroll") for (int kk = 0; kk < 4; ++kk) acc[m][n] =            \
        __builtin_amdgcn_mfma_f32_16x16x32_bf16(a[m][kk], bfr[kk], acc[m][n],   \
                                                0, 0, 0);                       \
  }

__global__ __launch_bounds__(256) void k_convert(const float* __restrict__ feat,
                                                 uint16_t* __restrict__ featB) {
  int idx = blockIdx.x * 256 + threadIdx.x;
  int nr = idx >> 7, d = idx & 127;
  int r = ((nr & 511) << 3) | (nr >> 9);
  __hip_bfloat16 h = __float2bfloat16(feat[r * D_ + d]);
  featB[idx] = *reinterpret_cast<uint16_t*>(&h);
}

__global__ __launch_bounds__(256) void k_pass1(const uint16_t* __restrict__ featB,
                                               float* __restrict__ R,
                                               float* __restrict__ P) {
  __shared__ alignas(16) uint16_t At[128 * 128];
  __shared__ alignas(16) uint16_t Bt[64 * 128];
  TILE_PREAMBLE();
  const int rc = blockIdx.x >> 3, jb = blockIdx.x & 7;
  const int rb = rc << 7, cb = jb << 9;
  const int kbase = rb & 511;
  LOAD_A(rb);
  __syncthreads();
  bf16x8 a[2][4];
  READ_AFRAGS();
  float rsum[2][4];
#pragma unroll
  for (int m = 0; m < 2; ++m)
#pragma unroll
    for (int q = 0; q < 4; ++q) rsum[m][q] = 0.f;
  for (int t8 = 0; t8 < 8; ++t8) {
    __syncthreads();
    LOAD_B(cb + t8 * 64);
    __syncthreads();
    f32x4 acc[2][4];
    COMPUTE_ACC();
#pragma unroll
    for (int m = 0; m < 2; ++m)
#pragma unroll
      for (int n = 0; n < 4; ++n)
#pragma unroll
        for (int q = 0; q < 4; ++q) {
          float v = __expf(acc[m][n][q] * TINV);
          rsum[m][q] += v;
          int row_local = w * 32 + m * 16 + rq + q;
          if (t8 * 64 + n * 16 + r0 == kbase + row_local)
            P[(size_t)(rb + row_local) * 8 + jb] = v;
        }
  }
#pragma unroll
  for (int m = 0; m < 2; ++m)
#pragma unroll
    for (int q = 0; q < 4; ++q) {
      float s = rsum[m][q];
      s += __shfl_xor(s, 1); s += __shfl_xor(s, 2);
      s += __shfl_xor(s, 4); s += __shfl_xor(s, 8);
      if (r0 == 0) R[(size_t)(rb + w * 32 + m * 16 + rq + q) * 8 + jb] = s;
    }
}

__global__ __launch_bounds__(256) void k_pass2_off(const uint16_t* __restrict__ featB,
                                                   const float* __restrict__ R,
                                                   const float* __restrict__ P,
                                                   double* __restrict__ p_off) {
  const int rc = blockIdx.x >> 3, jb = blockIdx.x & 7;
  const int rb = rc << 7, cb = jb << 9;
  const int i = rb >> 9;
  if (jb == i) {
    if (threadIdx.x == 0) p_off[blockIdx.x] = 0.0;
    return;
  }
  __shared__ alignas(16) uint16_t At[128 * 128];
  __shared__ alignas(16) uint16_t Bt[64 * 128];
  __shared__ double sm[4];
  TILE_PREAMBLE();
  LOAD_A(rb);
  __syncthreads();
  bf16x8 a[2][4];
  READ_AFRAGS();
  float inv[2][4], prod[2][4];
#pragma unroll
  for (int m = 0; m < 2; ++m)
#pragma unroll
    for (int q = 0; q < 4; ++q) {
      int g = rb + w * 32 + m * 16 + rq + q;
      float Ri = R[(size_t)g * 8 + i];
      float Rj = R[(size_t)g * 8 + jb];
      float Egg = P[(size_t)g * 8 + i];
      inv[m][q] = 1.f / (Ri + Rj - Egg);
      prod[m][q] = 1.f;
    }
  for (int t8 = 0; t8 < 8; ++t8) {
    __syncthreads();
    LOAD_B(cb + t8 * 64);
    __syncthreads();
    f32x4 acc[2][4];
    COMPUTE_ACC();
#pragma unroll
    for (int m = 0; m < 2; ++m)
#pragma unroll
      for (int n = 0; n < 4; ++n)
#pragma unroll
        for (int q = 0; q < 4; ++q)
          prod[m][q] *= (1.f - __expf(acc[m][n][q] * TINV) * inv[m][q]);
  }
  float lsum = 0.f;
#pragma unroll
  for (int m = 0; m < 2; ++m)
#pragma unroll
    for (int q = 0; q < 4; ++q) {
      float pr = prod[m][q];
      pr *= __shfl_xor(pr, 1); pr *= __shfl_xor(pr, 2);
      pr *= __shfl_xor(pr, 4); pr *= __shfl_xor(pr, 8);
      lsum += __logf(pr);
    }
  if (r0 != 0) lsum = 0.f;
  lsum += __shfl_xor(lsum, 16);
  lsum += __shfl_xor(lsum, 32);
  if (lane == 0) sm[w] = (double)lsum;
  __syncthreads();
  if (t == 0) p_off[blockIdx.x] = sm[0] + sm[1] + sm[2] + sm[3];
}

__global__ __launch_bounds__(256) void k_pass2_diag(const uint16_t* __restrict__ featB,
                                                    const float* __restrict__ R,
                                                    const float* __restrict__ P,
                                                    double* __restrict__ p_diag) {
  __shared__ alignas(16) uint16_t At[128 * 128];
  __shared__ alignas(16) uint16_t Bt[64 * 128];
  __shared__ double sm[4];
  TILE_PREAMBLE();
  const int rc = blockIdx.x;
  const int rb = rc << 7;
  const int i = rb >> 9;
  const int cb = i << 9;
  const int kbase = rb & 511;
  LOAD_A(rb);
  __syncthreads();
  bf16x8 a[2][4];
  READ_AFRAGS();
  float inv[2][4][8], prod[2][4][8];
#pragma unroll
  for (int m = 0; m < 2; ++m)
#pragma unroll
    for (int q = 0; q < 4; ++q) {
      int g = rb + w * 32 + m * 16 + rq + q;
      float Ri = R[(size_t)g * 8 + i];
      float Egg = P[(size_t)g * 8 + i];
#pragma unroll
      for (int j = 0; j < 8; ++j) {
        float Rj = R[(size_t)g * 8 + j];
        float dv = (j == i) ? (2.f * Ri - Egg) : (Ri + Rj - Egg);
        inv[m][q][j] = 1.f / dv;
        prod[m][q][j] = 1.f;
      }
    }
  for (int t8 = 0; t8 < 8; ++t8) {
    __syncthreads();
    LOAD_B(cb + t8 * 64);
    __syncthreads();
    f32x4 acc[2][4];
    COMPUTE_ACC();
#pragma unroll
    for (int m = 0; m < 2; ++m)
#pragma unroll
      for (int n = 0; n < 4; ++n)
#pragma unroll
        for (int q = 0; q < 4; ++q) {
          float e = __expf(acc[m][n][q] * TINV);
          int row_local = w * 32 + m * 16 + rq + q;
          if (t8 * 64 + n * 16 + r0 == kbase + row_local) e = 0.f;
#pragma unroll
          for (int j = 0; j < 8; ++j) prod[m][q][j] *= (1.f - e * inv[m][q][j]);
        }
  }
  float lsum = 0.f;
#pragma unroll
  for (int m = 0; m < 2; ++m)
#pragma unroll
    for (int q = 0; q < 4; ++q)
#pragma unroll
      for (int j = 0; j < 8; ++j) {
        float pr = prod[m][q][j];
        pr *= __shfl_xor(pr, 1); pr *= __shfl_xor(pr, 2);
        pr *= __shfl_xor(pr, 4); pr *= __shfl_xor(pr, 8);
        float lg = __logf(pr);
        lsum += (j == i) ? 4.f * lg : lg;
      }
  if (r0 != 0) lsum = 0.f;
  lsum += __shfl_xor(lsum, 16);
  lsum += __shfl_xor(lsum, 32);
  if (lane == 0) sm[w] = (double)lsum;
  __syncthreads();
  if (t == 0) p_diag[blockIdx.x] = sm[0] + sm[1] + sm[2] + sm[3];
}

__global__ __launch_bounds__(256) void k_corr(const float* __restrict__ R,
                                              const float* __restrict__ P,
                                              double* __restrict__ p_corr) {
  __shared__ double sm[4];
  const int lane = threadIdx.x & 63, w = threadIdx.x >> 6;
  int tid = blockIdx.x * 256 + threadIdx.x;
  int g = tid >> 3, j = tid & 7, i = g >> 9;
  float Ri = R[(size_t)g * 8 + i];
  float Egg = P[(size_t)g * 8 + i];
  float val;
  if (j != i) {
    float dv = Ri + R[(size_t)g * 8 + j] - Egg;
    float pmt = P[(size_t)g * 8 + j] / dv;
    val = __logf(pmt) - __logf(1.f - pmt);
  } else {
    float dv = 2.f * Ri - Egg;
    float pmt = Egg / dv;
    val = 2.f * __logf(pmt);
  }
  double dval = (double)val;
#pragma unroll
  for (int o = 32; o; o >>= 1) dval += __shfl_xor(dval, o);
  if (lane == 0) sm[w] = dval;
  __syncthreads();
  if (threadIdx.x == 0) p_corr[blockIdx.x] = sm[0] + sm[1] + sm[2] + sm[3];
}

__global__ __launch_bounds__(256) void k_ce(const float* __restrict__ Pr,
                                            const int* __restrict__ labels,
                                            double* __restrict__ part) {
  __shared__ double sm[4];
  const int lane = threadIdx.x & 63, w = threadIdx.x >> 6;
  const int row = (blockIdx.x << 2) + w;
  const float* pr = Pr + (size_t)row * C_;
  float mx = -3.0e38f;
  for (int k = lane; k < C_; k += 64) mx = fmaxf(mx, pr[k]);
#pragma unroll
  for (int o = 32; o; o >>= 1) mx = fmaxf(mx, __shfl_xor(mx, o));
  float s = 0.f;
  for (int k = lane; k < C_; k += 64) s += __expf(pr[k] - mx);
#pragma unroll
  for (int o = 32; o; o >>= 1) s += __shfl_xor(s, o);
  if (lane == 0) sm[w] = (double)(__logf(s) + mx - pr[labels[row]]);
  __syncthreads();
  if (threadIdx.x == 0) part[blockIdx.x] = sm[0] + sm[1] + sm[2] + sm[3];
}

__global__ __launch_bounds__(256) void k_final(const double* __restrict__ p_off,
                                               const double* __restrict__ p_diag,
                                               const double* __restrict__ p_corr,
                                               const double* __restrict__ p_ce,
                                               float* __restrict__ out) {
  __shared__ double sm[8];
  const int t = threadIdx.x, lane = t & 63, w = t >> 6;
  double nce = p_off[t];
  if (t < 32) nce += p_diag[t];
  if (t < 128) nce += p_corr[t];
  double ce = 0.0;
  for (int k = t; k < 1024; k += 256) ce += p_ce[k];
#pragma unroll
  for (int o = 32; o; o >>= 1) {
    nce += __shfl_xor(nce, o);
    ce += __shfl_xor(ce, o);
  }
  if (lane == 0) { sm[w] = nce; sm[4 + w] = ce; }
  __syncthreads();
  if (t == 0) {
    double tn = sm[0] + sm[1] + sm[2] + sm[3];
    double tc = sm[4] + sm[5] + sm[6] + sm[7];
    out[0] = ALPHA_ * (-(float)(tn / 1024.0)) + (float)(tc / 4096.0);
  }
}

__global__ void k_sentinel(float* out) {
  if (threadIdx.x == 0) out[0] = 12345.0f;
}

extern "C" void kernel_launch(void* const* d_in, const int* in_sizes, int n_in,
                              void* d_out, int out_size, void* d_ws, size_t ws_size,
                              hipStream_t stream) {
  const float* predicts = (const float*)d_in[0];
  const int* labels = (const int*)d_in[1];
  const float* features = (const float*)d_in[2];

  char* ws = (char*)d_ws;
  const size_t offFeatB = 0;                   // 1 MiB
  const size_t offR = 1048576;                 // 128 KiB
  const size_t offP = offR + 131072;           // 128 KiB
  const size_t offNce = offP + 131072;         // 512 doubles
  const size_t offCe = offNce + 4096;          // 512 doubles
  const size_t offPoff = offCe + 4096;         // 256 doubles (fallback)
  const size_t offPdiag = offPoff + 2048;      // 32 doubles
  const size_t offPcorr = offPdiag + 256;      // 128 doubles
  const size_t offPceOld = offPcorr + 1024;    // 1024 doubles
  const size_t need = offPceOld + 8192;

  float* out = (float*)d_out;
  if (ws_size < need) {
    k_sentinel<<<1, 64, 0, stream>>>(out);
    return;
  }

  uint16_t* featB = (uint16_t*)(ws + offFeatB);
  float* R = (float*)(ws + offR);
  float* P = (float*)(ws + offP);
  double* p_nce = (double*)(ws + offNce);
  double* p_ce = (double*)(ws + offCe);

  void* args[] = {(void*)&features, (void*)&predicts, (void*)&labels,
                  (void*)&featB,    (void*)&R,        (void*)&P,
                  (void*)&p_nce,    (void*)&p_ce,     (void*)&out};
  hipError_t err = hipLaunchCooperativeKernel((const void*)k_all, dim3(512),
                                              dim3(256), args, 0, stream);
  if (err == hipSuccess) return;
  (void)hipGetLastError();  // clear, fall back to multi-kernel path

  double* p_off = (double*)(ws + offPoff);
  double* p_diag = (double*)(ws + offPdiag);
  double* p_corr = (double*)(ws + offPcorr);
  double* p_ce_old = (double*)(ws + offPceOld);

  k_convert<<<2048, 256, 0, stream>>>(features, featB);
  k_pass1<<<256, 256, 0, stream>>>(featB, R, P);
  k_pass2_off<<<256, 256, 0, stream>>>(featB, R, P, p_off);
  k_pass2_diag<<<32, 256, 0, stream>>>(featB, R, P, p_diag);
  k_corr<<<128, 256, 0, stream>>>(R, P, p_corr);
  k_ce<<<1024, 256, 0, stream>>>(predicts, labels, p_ce_old);
  k_final<<<1, 256, 0, stream>>>(p_off, p_diag, p_corr, p_ce_old, out);
}

// Round 6
// 58.043 us; speedup vs baseline: 5.5523x; 5.5523x over previous
//
#include <hip/hip_runtime.h>
#include <hip/hip_bf16.h>
#include <stdint.h>

#define N_ 4096
#define D_ 128
#define C_ 400
#define TINV 10.0f
#define ALPHA_ 0.03f

typedef __bf16 bf16x8 __attribute__((ext_vector_type(8)));
typedef float f32x4 __attribute__((ext_vector_type(4)));

__device__ __forceinline__ void load16(const void* g, void* l) {
  __builtin_amdgcn_global_load_lds(
      (const __attribute__((address_space(1))) uint32_t*)g,
      (__attribute__((address_space(3))) uint32_t*)l, 16, 0, 0);
}

// ---- K0: convert features f32->bf16 (row-permuted new_r=(r%8)*512+r/8, float4
//          vectorized) + cross-entropy partials (8 rows/block).
__global__ __launch_bounds__(256) void k_prep(const float* __restrict__ feat,
                                              const float* __restrict__ predicts,
                                              const int* __restrict__ labels,
                                              uint16_t* __restrict__ featB,
                                              double* __restrict__ p_ce) {
  __shared__ double smr[4];
  const int t = threadIdx.x, bid = blockIdx.x;
  const int lane = t & 63, w = t >> 6;

  int idx4 = bid * 256 + t;  // 131072 float4 tasks
  int nr = idx4 >> 5, d4 = idx4 & 31;
  int r = ((nr & 511) << 3) | (nr >> 9);
  float4 v = reinterpret_cast<const float4*>(feat)[r * 32 + d4];
  __hip_bfloat16 h0 = __float2bfloat16(v.x), h1 = __float2bfloat16(v.y),
                 h2 = __float2bfloat16(v.z), h3 = __float2bfloat16(v.w);
  ushort4 o;
  o.x = *(uint16_t*)&h0; o.y = *(uint16_t*)&h1;
  o.z = *(uint16_t*)&h2; o.w = *(uint16_t*)&h3;
  reinterpret_cast<ushort4*>(featB)[idx4] = o;

  double ce = 0.0;
#pragma unroll
  for (int s = 0; s < 2; ++s) {
    int row = bid * 8 + w * 2 + s;
    const float* pr = predicts + (size_t)row * C_;
    float mx = -3.0e38f;
    for (int k = lane; k < C_; k += 64) mx = fmaxf(mx, pr[k]);
#pragma unroll
    for (int o2 = 32; o2; o2 >>= 1) mx = fmaxf(mx, __shfl_xor(mx, o2));
    float sum = 0.f;
    for (int k = lane; k < C_; k += 64) sum += __expf(pr[k] - mx);
#pragma unroll
    for (int o2 = 32; o2; o2 >>= 1) sum += __shfl_xor(sum, o2);
    ce += (double)(__logf(sum) + mx - pr[labels[row]]);
  }
  if (lane == 0) smr[w] = ce;
  __syncthreads();
  if (t == 0) p_ce[bid] = smr[0] + smr[1] + smr[2] + smr[3];
}

// ---- K1: single Gram sweep. Block (rc 0..31, jb 0..7): rows rb=rc*128,
// cols cb=jb*512. Per (row g, col-block jb) computes power sums
//   S1,S2,S3[g][jb] = sum_{c in blk jb, c != g} E^k  (E = exp(G/T); the
//   diagonal c==g is excluded at accumulation only when jb==own block)
// and P[g][jb] = E at the partner column (for jb==own block this is Egg).
// LDS st-swizzle byte^=((row&7)<<4), inverse-swizzled global_load_lds source.
__global__ __launch_bounds__(256) void k_sweep(const uint16_t* __restrict__ featB,
                                               float* __restrict__ S1,
                                               float* __restrict__ S2,
                                               float* __restrict__ S3,
                                               float* __restrict__ P) {
  __shared__ alignas(16) uint16_t At[128 * 128];
  __shared__ alignas(16) uint16_t Bt[64 * 128];
  const int t = threadIdx.x;
  const int lane = t & 63, w = t >> 6;
  const int r0 = lane & 15, kq = lane >> 4, rq = kq << 2;
  const char* fb = (const char*)featB;
  const int rc = blockIdx.x >> 3, jb = blockIdx.x & 7;
  const int rb = rc << 7, cb = jb << 9;
  const int ib = rb >> 9, kbase = rb & 511;
  const bool own = (jb == ib);

#pragma unroll
  for (int it = 0; it < 8; ++it) {
    int L = it * 4096 + t * 16;
    int row = L >> 8;
    int kbs = (L & 255) ^ ((row & 7) << 4);
    load16(fb + (size_t)(rb + row) * 256 + kbs, (char*)At + L);
  }
  __syncthreads();
  bf16x8 a[2][4];
#pragma unroll
  for (int m = 0; m < 2; ++m) {
    int ra = w * 32 + m * 16 + r0;
#pragma unroll
    for (int kk = 0; kk < 4; ++kk)
      a[m][kk] = *(const bf16x8*)((const char*)At + ra * 256 +
                                  ((kk * 64 + kq * 16) ^ ((ra & 7) << 4)));
  }

  float s1[2][4], s2[2][4], s3[2][4];
#pragma unroll
  for (int m = 0; m < 2; ++m)
#pragma unroll
    for (int q = 0; q < 4; ++q) { s1[m][q] = 0.f; s2[m][q] = 0.f; s3[m][q] = 0.f; }

  for (int t8 = 0; t8 < 8; ++t8) {
    __syncthreads();
#pragma unroll
    for (int it = 0; it < 4; ++it) {
      int L = it * 4096 + t * 16;
      int row = L >> 8;
      int kbs = (L & 255) ^ ((row & 7) << 4);
      load16(fb + (size_t)(cb + t8 * 64 + row) * 256 + kbs, (char*)Bt + L);
    }
    __syncthreads();
    f32x4 acc[2][4];
#pragma unroll
    for (int m = 0; m < 2; ++m)
#pragma unroll
      for (int n = 0; n < 4; ++n) acc[m][n] = (f32x4)0.0f;
#pragma unroll
    for (int n = 0; n < 4; ++n) {
      bf16x8 bfr[4];
      int cl = n * 16 + r0;
#pragma unroll
      for (int kk = 0; kk < 4; ++kk)
        bfr[kk] = *(const bf16x8*)((const char*)Bt + cl * 256 +
                                   ((kk * 64 + kq * 16) ^ ((cl & 7) << 4)));
#pragma unroll
      for (int m = 0; m < 2; ++m)
#pragma unroll
        for (int kk = 0; kk < 4; ++kk)
          acc[m][n] = __builtin_amdgcn_mfma_f32_16x16x32_bf16(a[m][kk], bfr[kk],
                                                              acc[m][n], 0, 0, 0);
    }
#pragma unroll
    for (int m = 0; m < 2; ++m)
#pragma unroll
      for (int n = 0; n < 4; ++n)
#pragma unroll
        for (int q = 0; q < 4; ++q) {
          float e = __expf(acc[m][n][q] * TINV);
          int rl = w * 32 + m * 16 + rq + q;
          if (t8 * 64 + n * 16 + r0 == kbase + rl) {
            P[(size_t)(rb + rl) * 8 + jb] = e;  // partner (== Egg when own)
            if (own) e = 0.f;                   // exclude diagonal from sums
          }
          s1[m][q] += e;
          s2[m][q] += e * e;
          s3[m][q] += e * e * e;
        }
  }
#pragma unroll
  for (int m = 0; m < 2; ++m)
#pragma unroll
    for (int q = 0; q < 4; ++q) {
      float v1 = s1[m][q], v2 = s2[m][q], v3 = s3[m][q];
#pragma unroll
      for (int o2 = 1; o2 <= 8; o2 <<= 1) {
        v1 += __shfl_xor(v1, o2);
        v2 += __shfl_xor(v2, o2);
        v3 += __shfl_xor(v3, o2);
      }
      if (r0 == 0) {
        size_t g = (size_t)(rb + w * 32 + m * 16 + rq + q) * 8 + jb;
        S1[g] = v1; S2[g] = v2; S3[g] = v3;
      }
    }
}

// ---- K2: closed-form NCE from power sums + final reduce. One 1024-thread block.
// Off pair (i,j), row g in blk i:  div = S1'[g][i] + S1[g][j]
//   contrib = log(pmt) - log(1-pmt) - inv*(S1i+S1j + inv*((S2i+S2j)/2 + inv*(S3i+S3j)/3))
// Diag pair: div = 2*S1'[g][i] + Egg
//   contrib = 2*log(Egg/div) - 4*inv*(S1i + inv*(S2i/2 + inv*S3i/3))
__global__ __launch_bounds__(1024) void k_post(const float* __restrict__ S1,
                                               const float* __restrict__ S2,
                                               const float* __restrict__ S3,
                                               const float* __restrict__ P,
                                               const double* __restrict__ p_ce,
                                               float* __restrict__ out) {
  __shared__ double smn[16], smc[16];
  const int t = threadIdx.x, lane = t & 63, w = t >> 6;
  double nce = 0.0;
  for (int task = t; task < 32768; task += 1024) {
    int g = task >> 3, j = task & 7, i = g >> 9;
    float s1i = S1[(size_t)g * 8 + i];
    float s2i = S2[(size_t)g * 8 + i];
    float s3i = S3[(size_t)g * 8 + i];
    float Egg = P[(size_t)g * 8 + i];
    float val;
    if (j != i) {
      float s1j = S1[(size_t)g * 8 + j];
      float s2j = S2[(size_t)g * 8 + j];
      float s3j = S3[(size_t)g * 8 + j];
      float div = s1i + s1j;
      float inv = 1.f / div;
      float pmt = P[(size_t)g * 8 + j] * inv;
      float Ls = (s1i + s1j) +
                 inv * (0.5f * (s2i + s2j) + inv * (0.333333333f * (s3i + s3j)));
      val = __logf(pmt) - __logf(1.f - pmt) - inv * Ls;
    } else {
      float div = 2.f * s1i + Egg;
      float inv = 1.f / div;
      float pmt = Egg * inv;
      float Ls = s1i + inv * (0.5f * s2i + inv * (0.333333333f * s3i));
      val = 2.f * __logf(pmt) - 4.f * inv * Ls;
    }
    nce += (double)val;
  }
  double ce = (t < 512) ? p_ce[t] : 0.0;
#pragma unroll
  for (int o2 = 32; o2; o2 >>= 1) {
    nce += __shfl_xor(nce, o2);
    ce += __shfl_xor(ce, o2);
  }
  if (lane == 0) { smn[w] = nce; smc[w] = ce; }
  __syncthreads();
  if (t == 0) {
    double tn = 0.0, tc = 0.0;
#pragma unroll
    for (int k = 0; k < 16; ++k) { tn += smn[k]; tc += smc[k]; }
    out[0] = ALPHA_ * (-(float)(tn / 1024.0)) + (float)(tc / 4096.0);
  }
}

__global__ void k_sentinel(float* out) {
  if (threadIdx.x == 0) out[0] = 12345.0f;
}

extern "C" void kernel_launch(void* const* d_in, const int* in_sizes, int n_in,
                              void* d_out, int out_size, void* d_ws, size_t ws_size,
                              hipStream_t stream) {
  const float* predicts = (const float*)d_in[0];
  const int* labels = (const int*)d_in[1];
  const float* features = (const float*)d_in[2];

  char* ws = (char*)d_ws;
  const size_t offFeatB = 0;                 // 1 MiB
  const size_t offS1 = 1048576;              // 4096*8*4 = 128 KiB each
  const size_t offS2 = offS1 + 131072;
  const size_t offS3 = offS2 + 131072;
  const size_t offP = offS3 + 131072;
  const size_t offCe = offP + 131072;        // 512 doubles
  const size_t need = offCe + 4096;

  float* out = (float*)d_out;
  if (ws_size < need) {
    k_sentinel<<<1, 64, 0, stream>>>(out);
    return;
  }

  uint16_t* featB = (uint16_t*)(ws + offFeatB);
  float* S1 = (float*)(ws + offS1);
  float* S2 = (float*)(ws + offS2);
  float* S3 = (float*)(ws + offS3);
  float* P = (float*)(ws + offP);
  double* p_ce = (double*)(ws + offCe);

  k_prep<<<512, 256, 0, stream>>>(features, predicts, labels, featB, p_ce);
  k_sweep<<<256, 256, 0, stream>>>(featB, S1, S2, S3, P);
  k_post<<<1, 1024, 0, stream>>>(S1, S2, S3, P, p_ce, out);
}

// Round 7
// 47.812 us; speedup vs baseline: 6.7404x; 1.2140x over previous
//
#include <hip/hip_runtime.h>
#include <hip/hip_bf16.h>
#include <stdint.h>

#define N_ 4096
#define D_ 128
#define C_ 400
#define TINV 10.0f
#define ALPHA_ 0.03f

typedef __bf16 bf16x8 __attribute__((ext_vector_type(8)));
typedef float f32x4 __attribute__((ext_vector_type(4)));

__device__ __forceinline__ void load16(const void* g, void* l) {
  __builtin_amdgcn_global_load_lds(
      (const __attribute__((address_space(1))) uint32_t*)g,
      (__attribute__((address_space(3))) uint32_t*)l, 16, 0, 0);
}

// ---- K0: convert features f32->bf16 (row-permuted new_r=(r%8)*512+r/8, float4
//          vectorized) + cross-entropy partials (8 rows/block) + counter reset.
__global__ __launch_bounds__(256) void k_prep(const float* __restrict__ feat,
                                              const float* __restrict__ predicts,
                                              const int* __restrict__ labels,
                                              uint16_t* __restrict__ featB,
                                              double* __restrict__ p_ce,
                                              unsigned int* __restrict__ counter) {
  __shared__ double smr[4];
  const int t = threadIdx.x, bid = blockIdx.x;
  const int lane = t & 63, w = t >> 6;
  if (bid == 0 && t == 0) counter[0] = 0;  // reset finalize counter each call

  int idx4 = bid * 256 + t;  // 131072 float4 tasks
  int nr = idx4 >> 5, d4 = idx4 & 31;
  int r = ((nr & 511) << 3) | (nr >> 9);
  float4 v = reinterpret_cast<const float4*>(feat)[r * 32 + d4];
  __hip_bfloat16 h0 = __float2bfloat16(v.x), h1 = __float2bfloat16(v.y),
                 h2 = __float2bfloat16(v.z), h3 = __float2bfloat16(v.w);
  ushort4 o;
  o.x = *(uint16_t*)&h0; o.y = *(uint16_t*)&h1;
  o.z = *(uint16_t*)&h2; o.w = *(uint16_t*)&h3;
  reinterpret_cast<ushort4*>(featB)[idx4] = o;

  double ce = 0.0;
#pragma unroll
  for (int s = 0; s < 2; ++s) {
    int row = bid * 8 + w * 2 + s;
    const float* pr = predicts + (size_t)row * C_;
    float mx = -3.0e38f;
    for (int k = lane; k < C_; k += 64) mx = fmaxf(mx, pr[k]);
#pragma unroll
    for (int o2 = 32; o2; o2 >>= 1) mx = fmaxf(mx, __shfl_xor(mx, o2));
    float sum = 0.f;
    for (int k = lane; k < C_; k += 64) sum += __expf(pr[k] - mx);
#pragma unroll
    for (int o2 = 32; o2; o2 >>= 1) sum += __shfl_xor(sum, o2);
    ce += (double)(__logf(sum) + mx - pr[labels[row]]);
  }
  if (lane == 0) smr[w] = ce;
  __syncthreads();
  if (t == 0) p_ce[bid] = smr[0] + smr[1] + smr[2] + smr[3];
}

// ---- K1: single Gram sweep, 64-row x 512-col tile per block (512 blocks).
// Per (row g, col-block jb): power sums S1,S2,S3 (diagonal c==g excluded for the
// own block) and partner element P. LDS st-swizzle byte^=((row&7)<<4) via
// inverse-swizzled global_load_lds source + swizzled ds_read.
__global__ __launch_bounds__(256, 4) void k_sweep(const uint16_t* __restrict__ featB,
                                                  float* __restrict__ S1,
                                                  float* __restrict__ S2,
                                                  float* __restrict__ S3,
                                                  float* __restrict__ P) {
  __shared__ alignas(16) uint16_t At[64 * 128];
  __shared__ alignas(16) uint16_t Bt[64 * 128];
  const int t = threadIdx.x;
  const int lane = t & 63, w = t >> 6;
  const int r0 = lane & 15, kq = lane >> 4, rq = kq << 2;
  const char* fb = (const char*)featB;
  const int rc = blockIdx.x >> 3, jb = blockIdx.x & 7;
  const int rb = rc << 6, cb = jb << 9;
  const int ib = rb >> 9, kbase = rb & 511;
  const bool own = (jb == ib);

#pragma unroll
  for (int it = 0; it < 4; ++it) {
    int L = it * 4096 + t * 16;
    int row = L >> 8;
    int kbs = (L & 255) ^ ((row & 7) << 4);
    load16(fb + (size_t)(rb + row) * 256 + kbs, (char*)At + L);
  }
  __syncthreads();
  bf16x8 a[4];
  {
    int ra = (w << 4) + r0;
#pragma unroll
    for (int kk = 0; kk < 4; ++kk)
      a[kk] = *(const bf16x8*)((const char*)At + ra * 256 +
                               ((kk * 64 + kq * 16) ^ ((ra & 7) << 4)));
  }

  float s1[4] = {0.f, 0.f, 0.f, 0.f};
  float s2[4] = {0.f, 0.f, 0.f, 0.f};
  float s3[4] = {0.f, 0.f, 0.f, 0.f};

  for (int t8 = 0; t8 < 8; ++t8) {
    __syncthreads();
#pragma unroll
    for (int it = 0; it < 4; ++it) {
      int L = it * 4096 + t * 16;
      int row = L >> 8;
      int kbs = (L & 255) ^ ((row & 7) << 4);
      load16(fb + (size_t)(cb + t8 * 64 + row) * 256 + kbs, (char*)Bt + L);
    }
    __syncthreads();
    f32x4 acc[4];
#pragma unroll
    for (int n = 0; n < 4; ++n) {
      acc[n] = (f32x4)0.0f;
      int cl = n * 16 + r0;
#pragma unroll
      for (int kk = 0; kk < 4; ++kk) {
        bf16x8 bfr = *(const bf16x8*)((const char*)Bt + cl * 256 +
                                      ((kk * 64 + kq * 16) ^ ((cl & 7) << 4)));
        acc[n] = __builtin_amdgcn_mfma_f32_16x16x32_bf16(a[kk], bfr, acc[n], 0, 0, 0);
      }
    }
#pragma unroll
    for (int n = 0; n < 4; ++n)
#pragma unroll
      for (int q = 0; q < 4; ++q) {
        float e = __expf(acc[n][q] * TINV);
        int rl = (w << 4) + rq + q;
        if (t8 * 64 + n * 16 + r0 == kbase + rl) {
          P[(size_t)(rb + rl) * 8 + jb] = e;  // partner (== Egg when own)
          if (own) e = 0.f;                   // exclude diagonal from sums
        }
        s1[q] += e;
        s2[q] += e * e;
        s3[q] += e * e * e;
      }
  }
#pragma unroll
  for (int q = 0; q < 4; ++q) {
    float v1 = s1[q], v2 = s2[q], v3 = s3[q];
#pragma unroll
    for (int o2 = 1; o2 <= 8; o2 <<= 1) {
      v1 += __shfl_xor(v1, o2);
      v2 += __shfl_xor(v2, o2);
      v3 += __shfl_xor(v3, o2);
    }
    if (r0 == 0) {
      size_t g = (size_t)(rb + (w << 4) + rq + q) * 8 + jb;
      S1[g] = v1; S2[g] = v2; S3[g] = v3;
    }
  }
}

// ---- K2: closed-form NCE from power sums, 32 blocks; deterministic last-block
// finalize (atomic counter) folds the final reduce into the same dispatch.
__global__ __launch_bounds__(256) void k_post(const float* __restrict__ S1,
                                              const float* __restrict__ S2,
                                              const float* __restrict__ S3,
                                              const float* __restrict__ P,
                                              const double* __restrict__ p_ce,
                                              double* __restrict__ p_nce,
                                              unsigned int* __restrict__ counter,
                                              float* __restrict__ out) {
  __shared__ double smr[4];
  __shared__ int isLast;
  const int t = threadIdx.x, b = blockIdx.x;
  const int lane = t & 63, w = t >> 6;
  double nce = 0.0;
#pragma unroll
  for (int s = 0; s < 4; ++s) {
    int task = b * 1024 + s * 256 + t;  // 0..32767
    int g = task >> 3, j = task & 7, i = g >> 9;
    float s1i = S1[(size_t)g * 8 + i];
    float s2i = S2[(size_t)g * 8 + i];
    float s3i = S3[(size_t)g * 8 + i];
    float Egg = P[(size_t)g * 8 + i];
    float val;
    if (j != i) {
      float s1j = S1[(size_t)g * 8 + j];
      float s2j = S2[(size_t)g * 8 + j];
      float s3j = S3[(size_t)g * 8 + j];
      float div = s1i + s1j;
      float inv = 1.f / div;
      float pmt = P[(size_t)g * 8 + j] * inv;
      float Ls = (s1i + s1j) +
                 inv * (0.5f * (s2i + s2j) + inv * (0.333333333f * (s3i + s3j)));
      val = __logf(pmt) - __logf(1.f - pmt) - inv * Ls;
    } else {
      float div = 2.f * s1i + Egg;
      float inv = 1.f / div;
      float pmt = Egg * inv;
      float Ls = s1i + inv * (0.5f * s2i + inv * (0.333333333f * s3i));
      val = 2.f * __logf(pmt) - 4.f * inv * Ls;
    }
    nce += (double)val;
  }
#pragma unroll
  for (int o2 = 32; o2; o2 >>= 1) nce += __shfl_xor(nce, o2);
  if (lane == 0) smr[w] = nce;
  __syncthreads();
  if (t == 0) {
    p_nce[b] = smr[0] + smr[1] + smr[2] + smr[3];
    __threadfence();
    unsigned int old = atomicAdd(counter, 1u);
    isLast = (old == 31u) ? 1 : 0;
  }
  __syncthreads();
  if (isLast) {
    __threadfence();
    double tn = (t < 32) ? p_nce[t] : 0.0;
    double tc = p_ce[t] + p_ce[t + 256];
#pragma unroll
    for (int o2 = 32; o2; o2 >>= 1) {
      tn += __shfl_xor(tn, o2);
      tc += __shfl_xor(tc, o2);
    }
    __shared__ double smn2[4], smc2[4];
    if (lane == 0) { smn2[w] = tn; smc2[w] = tc; }
    __syncthreads();
    if (t == 0) {
      double fn = smn2[0] + smn2[1] + smn2[2] + smn2[3];
      double fc = smc2[0] + smc2[1] + smc2[2] + smc2[3];
      out[0] = ALPHA_ * (-(float)(fn / 1024.0)) + (float)(fc / 4096.0);
    }
  }
}

__global__ void k_sentinel(float* out) {
  if (threadIdx.x == 0) out[0] = 12345.0f;
}

extern "C" void kernel_launch(void* const* d_in, const int* in_sizes, int n_in,
                              void* d_out, int out_size, void* d_ws, size_t ws_size,
                              hipStream_t stream) {
  const float* predicts = (const float*)d_in[0];
  const int* labels = (const int*)d_in[1];
  const float* features = (const float*)d_in[2];

  char* ws = (char*)d_ws;
  const size_t offFeatB = 0;                 // 1 MiB
  const size_t offS1 = 1048576;              // 4096*8*4 = 128 KiB each
  const size_t offS2 = offS1 + 131072;
  const size_t offS3 = offS2 + 131072;
  const size_t offP = offS3 + 131072;
  const size_t offCe = offP + 131072;        // 512 doubles
  const size_t offNce = offCe + 4096;        // 32 doubles
  const size_t offCnt = offNce + 256;        // 1 uint
  const size_t need = offCnt + 64;

  float* out = (float*)d_out;
  if (ws_size < need) {
    k_sentinel<<<1, 64, 0, stream>>>(out);
    return;
  }

  uint16_t* featB = (uint16_t*)(ws + offFeatB);
  float* S1 = (float*)(ws + offS1);
  float* S2 = (float*)(ws + offS2);
  float* S3 = (float*)(ws + offS3);
  float* P = (float*)(ws + offP);
  double* p_ce = (double*)(ws + offCe);
  double* p_nce = (double*)(ws + offNce);
  unsigned int* counter = (unsigned int*)(ws + offCnt);

  k_prep<<<512, 256, 0, stream>>>(features, predicts, labels, featB, p_ce, counter);
  k_sweep<<<512, 256, 0, stream>>>(featB, S1, S2, S3, P);
  k_post<<<32, 256, 0, stream>>>(S1, S2, S3, P, p_ce, p_nce, counter, out);
}

// Round 8
// 31.055 us; speedup vs baseline: 10.3773x; 1.5396x over previous
//
#include <hip/hip_runtime.h>
#include <hip/hip_bf16.h>
#include <stdint.h>

#define N_ 4096
#define D_ 128
#define C_ 400
#define TINV 10.0f
#define ALPHA_ 0.03f

typedef __bf16 bf16x8 __attribute__((ext_vector_type(8)));
typedef float f32x4 __attribute__((ext_vector_type(4)));

__device__ __forceinline__ void load16(const void* g, void* l) {
  __builtin_amdgcn_global_load_lds(
      (const __attribute__((address_space(1))) uint32_t*)g,
      (__attribute__((address_space(3))) uint32_t*)l, 16, 0, 0);
}

// ---- K0: convert features f32->bf16 (row-permuted new_r=(r%8)*512+r/8, float4
//          vectorized) + cross-entropy partials (8 rows/block) + counter reset.
__global__ __launch_bounds__(256) void k_prep(const float* __restrict__ feat,
                                              const float* __restrict__ predicts,
                                              const int* __restrict__ labels,
                                              uint16_t* __restrict__ featB,
                                              double* __restrict__ p_ce,
                                              unsigned int* __restrict__ counter) {
  __shared__ double smr[4];
  const int t = threadIdx.x, bid = blockIdx.x;
  const int lane = t & 63, w = t >> 6;
  if (bid == 0 && t == 0) counter[0] = 0;  // reset finalize counter each call

  int idx4 = bid * 256 + t;  // 131072 float4 tasks
  int nr = idx4 >> 5, d4 = idx4 & 31;
  int r = ((nr & 511) << 3) | (nr >> 9);
  float4 v = reinterpret_cast<const float4*>(feat)[r * 32 + d4];
  __hip_bfloat16 h0 = __float2bfloat16(v.x), h1 = __float2bfloat16(v.y),
                 h2 = __float2bfloat16(v.z), h3 = __float2bfloat16(v.w);
  ushort4 o;
  o.x = *(uint16_t*)&h0; o.y = *(uint16_t*)&h1;
  o.z = *(uint16_t*)&h2; o.w = *(uint16_t*)&h3;
  reinterpret_cast<ushort4*>(featB)[idx4] = o;

  double ce = 0.0;
#pragma unroll
  for (int s = 0; s < 2; ++s) {
    int row = bid * 8 + w * 2 + s;
    const float* pr = predicts + (size_t)row * C_;
    float mx = -3.0e38f;
    for (int k = lane; k < C_; k += 64) mx = fmaxf(mx, pr[k]);
#pragma unroll
    for (int o2 = 32; o2; o2 >>= 1) mx = fmaxf(mx, __shfl_xor(mx, o2));
    float sum = 0.f;
    for (int k = lane; k < C_; k += 64) sum += __expf(pr[k] - mx);
#pragma unroll
    for (int o2 = 32; o2; o2 >>= 1) sum += __shfl_xor(sum, o2);
    ce += (double)(__logf(sum) + mx - pr[labels[row]]);
  }
  if (lane == 0) smr[w] = ce;
  __syncthreads();
  if (t == 0) p_ce[bid] = smr[0] + smr[1] + smr[2] + smr[3];
}

// ---- K1: single Gram sweep, 64-row x 256-col tile per block (1024 blocks,
// 4 blocks/CU). Per (row g, col-block jb, half h): power-sum partials
// S1h,S2h,S3h (diagonal c==g excluded for the own block) and partner P
// (written by the unique half-block containing the partner column).
// LDS st-swizzle byte^=((row&7)<<4) via inverse-swizzled global source.
__global__ __launch_bounds__(256, 4) void k_sweep(const uint16_t* __restrict__ featB,
                                                  float* __restrict__ S1h,
                                                  float* __restrict__ S2h,
                                                  float* __restrict__ S3h,
                                                  float* __restrict__ P) {
  __shared__ alignas(16) uint16_t At[64 * 128];
  __shared__ alignas(16) uint16_t Bt[64 * 128];
  const int t = threadIdx.x;
  const int lane = t & 63, w = t >> 6;
  const int r0 = lane & 15, kq = lane >> 4, rq = kq << 2;
  const char* fb = (const char*)featB;
  const int rc = blockIdx.x >> 4, ch = blockIdx.x & 15;
  const int jb = ch >> 1, half = ch & 1;
  const int rb = rc << 6;
  const int cbase = (jb << 9) + (half << 8);   // global col start (256 cols)
  const int lc0 = half << 8;                   // local col offset within 512-block
  const int ib = rb >> 9, kbase = rb & 511;
  const bool own = (jb == ib);

#pragma unroll
  for (int it = 0; it < 4; ++it) {
    int L = it * 4096 + t * 16;
    int row = L >> 8;
    int kbs = (L & 255) ^ ((row & 7) << 4);
    load16(fb + (size_t)(rb + row) * 256 + kbs, (char*)At + L);
  }
  __syncthreads();
  bf16x8 a[4];
  {
    int ra = (w << 4) + r0;
#pragma unroll
    for (int kk = 0; kk < 4; ++kk)
      a[kk] = *(const bf16x8*)((const char*)At + ra * 256 +
                               ((kk * 64 + kq * 16) ^ ((ra & 7) << 4)));
  }

  float s1[4] = {0.f, 0.f, 0.f, 0.f};
  float s2[4] = {0.f, 0.f, 0.f, 0.f};
  float s3[4] = {0.f, 0.f, 0.f, 0.f};

  for (int t8 = 0; t8 < 4; ++t8) {
    __syncthreads();
#pragma unroll
    for (int it = 0; it < 4; ++it) {
      int L = it * 4096 + t * 16;
      int row = L >> 8;
      int kbs = (L & 255) ^ ((row & 7) << 4);
      load16(fb + (size_t)(cbase + t8 * 64 + row) * 256 + kbs, (char*)Bt + L);
    }
    __syncthreads();
    f32x4 acc[4];
#pragma unroll
    for (int n = 0; n < 4; ++n) {
      acc[n] = (f32x4)0.0f;
      int cl = n * 16 + r0;
#pragma unroll
      for (int kk = 0; kk < 4; ++kk) {
        bf16x8 bfr = *(const bf16x8*)((const char*)Bt + cl * 256 +
                                      ((kk * 64 + kq * 16) ^ ((cl & 7) << 4)));
        acc[n] = __builtin_amdgcn_mfma_f32_16x16x32_bf16(a[kk], bfr, acc[n], 0, 0, 0);
      }
    }
#pragma unroll
    for (int n = 0; n < 4; ++n)
#pragma unroll
      for (int q = 0; q < 4; ++q) {
        float e = __expf(acc[n][q] * TINV);
        int rl = (w << 4) + rq + q;
        if (lc0 + t8 * 64 + n * 16 + r0 == kbase + rl) {
          P[(size_t)(rb + rl) * 8 + jb] = e;  // partner (== Egg when own)
          if (own) e = 0.f;                   // exclude diagonal from sums
        }
        s1[q] += e;
        s2[q] += e * e;
        s3[q] += e * e * e;
      }
  }
#pragma unroll
  for (int q = 0; q < 4; ++q) {
    float v1 = s1[q], v2 = s2[q], v3 = s3[q];
#pragma unroll
    for (int o2 = 1; o2 <= 8; o2 <<= 1) {
      v1 += __shfl_xor(v1, o2);
      v2 += __shfl_xor(v2, o2);
      v3 += __shfl_xor(v3, o2);
    }
    if (r0 == 0) {
      size_t gi = ((size_t)(rb + (w << 4) + rq + q) * 8 + jb) * 2 + half;
      S1h[gi] = v1; S2h[gi] = v2; S3h[gi] = v3;
    }
  }
}

// ---- K2: closed-form NCE from power sums, 32 blocks; deterministic last-block
// finalize (atomic counter) folds the final reduce into the same dispatch.
__global__ __launch_bounds__(256) void k_post(const float* __restrict__ S1h,
                                              const float* __restrict__ S2h,
                                              const float* __restrict__ S3h,
                                              const float* __restrict__ P,
                                              const double* __restrict__ p_ce,
                                              double* __restrict__ p_nce,
                                              unsigned int* __restrict__ counter,
                                              float* __restrict__ out) {
  __shared__ double smr[4];
  __shared__ int isLast;
  const int t = threadIdx.x, b = blockIdx.x;
  const int lane = t & 63, w = t >> 6;
  double nce = 0.0;
#pragma unroll
  for (int s = 0; s < 4; ++s) {
    int task = b * 1024 + s * 256 + t;  // 0..32767
    int g = task >> 3, j = task & 7, i = g >> 9;
    size_t gi = ((size_t)g * 8 + i) * 2;
    float s1i = S1h[gi] + S1h[gi + 1];
    float s2i = S2h[gi] + S2h[gi + 1];
    float s3i = S3h[gi] + S3h[gi + 1];
    float Egg = P[(size_t)g * 8 + i];
    float val;
    if (j != i) {
      size_t gj = ((size_t)g * 8 + j) * 2;
      float s1j = S1h[gj] + S1h[gj + 1];
      float s2j = S2h[gj] + S2h[gj + 1];
      float s3j = S3h[gj] + S3h[gj + 1];
      float div = s1i + s1j;
      float inv = 1.f / div;
      float pmt = P[(size_t)g * 8 + j] * inv;
      float Ls = (s1i + s1j) +
                 inv * (0.5f * (s2i + s2j) + inv * (0.333333333f * (s3i + s3j)));
      val = __logf(pmt) - __logf(1.f - pmt) - inv * Ls;
    } else {
      float div = 2.f * s1i + Egg;
      float inv = 1.f / div;
      float pmt = Egg * inv;
      float Ls = s1i + inv * (0.5f * s2i + inv * (0.333333333f * s3i));
      val = 2.f * __logf(pmt) - 4.f * inv * Ls;
    }
    nce += (double)val;
  }
#pragma unroll
  for (int o2 = 32; o2; o2 >>= 1) nce += __shfl_xor(nce, o2);
  if (lane == 0) smr[w] = nce;
  __syncthreads();
  if (t == 0) {
    p_nce[b] = smr[0] + smr[1] + smr[2] + smr[3];
    __threadfence();
    unsigned int old = atomicAdd(counter, 1u);
    isLast = (old == 31u) ? 1 : 0;
  }
  __syncthreads();
  if (isLast) {
    __threadfence();
    double tn = (t < 32) ? p_nce[t] : 0.0;
    double tc = p_ce[t] + p_ce[t + 256];
#pragma unroll
    for (int o2 = 32; o2; o2 >>= 1) {
      tn += __shfl_xor(tn, o2);
      tc += __shfl_xor(tc, o2);
    }
    __shared__ double smn2[4], smc2[4];
    if (lane == 0) { smn2[w] = tn; smc2[w] = tc; }
    __syncthreads();
    if (t == 0) {
      double fn = smn2[0] + smn2[1] + smn2[2] + smn2[3];
      double fc = smc2[0] + smc2[1] + smc2[2] + smc2[3];
      out[0] = ALPHA_ * (-(float)(fn / 1024.0)) + (float)(fc / 4096.0);
    }
  }
}

__global__ void k_sentinel(float* out) {
  if (threadIdx.x == 0) out[0] = 12345.0f;
}

extern "C" void kernel_launch(void* const* d_in, const int* in_sizes, int n_in,
                              void* d_out, int out_size, void* d_ws, size_t ws_size,
                              hipStream_t stream) {
  const float* predicts = (const float*)d_in[0];
  const int* labels = (const int*)d_in[1];
  const float* features = (const float*)d_in[2];

  char* ws = (char*)d_ws;
  const size_t offFeatB = 0;                  // 1 MiB
  const size_t offS1 = 1048576;               // 4096*8*2*4 = 256 KiB each
  const size_t offS2 = offS1 + 262144;
  const size_t offS3 = offS2 + 262144;
  const size_t offP = offS3 + 262144;         // 128 KiB
  const size_t offCe = offP + 131072;         // 512 doubles
  const size_t offNce = offCe + 4096;         // 32 doubles
  const size_t offCnt = offNce + 256;         // 1 uint
  const size_t need = offCnt + 64;

  float* out = (float*)d_out;
  if (ws_size < need) {
    k_sentinel<<<1, 64, 0, stream>>>(out);
    return;
  }

  uint16_t* featB = (uint16_t*)(ws + offFeatB);
  float* S1h = (float*)(ws + offS1);
  float* S2h = (float*)(ws + offS2);
  float* S3h = (float*)(ws + offS3);
  float* P = (float*)(ws + offP);
  double* p_ce = (double*)(ws + offCe);
  double* p_nce = (double*)(ws + offNce);
  unsigned int* counter = (unsigned int*)(ws + offCnt);

  k_prep<<<512, 256, 0, stream>>>(features, predicts, labels, featB, p_ce, counter);
  k_sweep<<<1024, 256, 0, stream>>>(featB, S1h, S2h, S3h, P);
  k_post<<<32, 256, 0, stream>>>(S1h, S2h, S3h, P, p_ce, p_nce, counter, out);
}